// Round 12
// baseline (34.337 us; speedup 1.0000x reference)
//
#include <hip/hip_runtime.h>
#include <hip/hip_fp16.h>

// Problem constants (match reference)
#define NRAYS 1048576
#define NV 32
#define ND 32
#define NF 6
#define NK 13  // 2F+1

typedef _Float16 h2 __attribute__((ext_vector_type(2)));
typedef float f4 __attribute__((ext_vector_type(4)));

__device__ __forceinline__ float fdot2acc(h2 a, h2 b, float c) {
#if __has_builtin(__builtin_amdgcn_fdot2)
    return __builtin_amdgcn_fdot2(a, b, c, false);
#else
    return c + (float)a.x * (float)b.x + (float)a.y * (float)b.y;
#endif
}

__device__ __forceinline__ h2 pack2(float a, float b) {
#if __has_builtin(__builtin_amdgcn_cvt_pkrtz)
    return __builtin_bit_cast(h2, __builtin_amdgcn_cvt_pkrtz(a, b));
#else
    h2 r; r.x = (_Float16)a; r.y = (_Float16)b; return r;
#endif
}

__device__ __forceinline__ float hwsin(float rev) {
#if __has_builtin(__builtin_amdgcn_sinf)
    return __builtin_amdgcn_sinf(rev);
#else
    return __sinf(6.28318530717958647692f * rev);
#endif
}
__device__ __forceinline__ float hwcos(float rev) {
#if __has_builtin(__builtin_amdgcn_cosf)
    return __builtin_amdgcn_cosf(rev);
#else
    return __cosf(6.28318530717958647692f * rev);
#endif
}

// ---------------------------------------------------------------------------
// Kernel A: pack f32 weights into the v&7-XOR-swizzled f16 image (see R5).
// dword idx = v*224 + i*32 + pos*4 + e; chunk at pos holds d-quad pos^(v&7).
__global__ void pack_weights_kernel(const float* __restrict__ weights,
                                    unsigned* __restrict__ wpack)
{
    int j = blockIdx.x * 256 + threadIdx.x;  // 0 .. 7167 (dwords)
    if (j >= NV * 7 * 32) return;
    int v = j / 224;
    int r = j - v * 224;
    int i = r >> 5;
    int c = r & 31;
    int pos = c >> 2;
    int e = c & 3;
    int q = pos ^ (v & 7);
    int d = 4 * q + e;
    float w0 = weights[v * (ND * NK) + d * NK + 2 * i];
    float w1 = (2 * i + 1 < NK) ? weights[v * (ND * NK) + d * NK + 2 * i + 1] : 0.f;
    wpack[j] = __builtin_bit_cast(unsigned, pack2(w0, w1));
}

// ---------------------------------------------------------------------------
// Main kernel. Block owns 256 contiguous rays.
// Prologue: each thread computes the basis for ITS ray ONCE (kills the x8
// redundancy that made the kernel VALU-bound: ~24.5us VALU -> ~17us) and
// shares it via s_bp; weights staged to LDS; all global loads before any
// store (stores-only vmcnt queue). Dot phase: 8 threads/ray, thread q owns
// d=4q..4q+3; per-iter 2xds_read_b128 bp (broadcast) + 7 weight b128
// (v&7-swizzled banks) + 28 fdot2 + 1 plain 16B store.
__global__ __launch_bounds__(256, 4) void VideoEmbedding_kernel(
    const float* __restrict__ times,
    const int* __restrict__ vids,
    const unsigned* __restrict__ wpack,
    float* __restrict__ out)
{
    __shared__ _Float16 wl[NV * 7 * ND * 2];  // 28672 B
    __shared__ unsigned s_bp[256 * 8];        //  8192 B (7 h2-pairs + pad)
    __shared__ unsigned char s_v[256];        //   256 B  -> 37120 B total

    const int tid = threadIdx.x;
    const int rbase = blockIdx.x * 256;

    // -------- prologue: all global loads, basis once per ray --------
    uint4 wst[7];
    {
        const uint4* src = reinterpret_cast<const uint4*>(wpack);
#pragma unroll
        for (int j = 0; j < 7; ++j)
            wst[j] = src[tid + j * 256];
    }
    const float t = times[rbase + tid];
    const int vid = vids[rbase + tid];

    {
        uint4* dst = reinterpret_cast<uint4*>(wl);
#pragma unroll
        for (int j = 0; j < 7; ++j)
            dst[tid + j * 256] = wst[j];
    }
    s_v[tid] = (unsigned char)vid;

    {   // basis for ray rbase+tid: seed trans (revolutions), double-angle up
        float sv[NF], cv[NF];
        sv[0] = hwsin(0.5f * t);
        cv[0] = hwcos(0.5f * t);
#pragma unroll
        for (int j = 1; j < NF; ++j) {
            float sj = sv[j - 1], cj = cv[j - 1];
            sv[j] = 2.f * sj * cj;
            cv[j] = fmaf(-2.f * sj, sj, 1.f);
        }
        uint4 lo, hi;
        lo.x = __builtin_bit_cast(unsigned, pack2(1.0f, sv[0]));
        lo.y = __builtin_bit_cast(unsigned, pack2(sv[1], sv[2]));
        lo.z = __builtin_bit_cast(unsigned, pack2(sv[3], sv[4]));
        lo.w = __builtin_bit_cast(unsigned, pack2(sv[5], cv[0]));
        hi.x = __builtin_bit_cast(unsigned, pack2(cv[1], cv[2]));
        hi.y = __builtin_bit_cast(unsigned, pack2(cv[3], cv[4]));
        hi.z = __builtin_bit_cast(unsigned, pack2(cv[5], 0.0f));  // pad = 0
        hi.w = 0u;
        reinterpret_cast<uint4*>(s_bp)[tid * 2] = lo;
        reinterpret_cast<uint4*>(s_bp)[tid * 2 + 1] = hi;
    }
    __syncthreads();

    const int q = tid & 7;
    const int g = tid >> 3;  // ray-group 0..31; slot = p*32+g

    uint4 wA[7], wB[7];
    {
        const int v = s_v[g];
        const unsigned b = (unsigned)v * 448u + (unsigned)(q ^ (v & 7)) * 8u;
#pragma unroll
        for (int i = 0; i < 7; ++i)
            wA[i] = *reinterpret_cast<const uint4*>(&wl[b + i * 64]);
    }

#define ITER(P, WCUR, WNEXT)                                                  \
    {                                                                         \
        if ((P) < 7) {  /* prefetch weights for slot P+1 */                   \
            const int nv = s_v[((P) + 1) * 32 + g];                           \
            const unsigned nb =                                               \
                (unsigned)nv * 448u + (unsigned)(q ^ (nv & 7)) * 8u;          \
            _Pragma("unroll")                                                 \
            for (int i = 0; i < 7; ++i)                                       \
                WNEXT[i] = *reinterpret_cast<const uint4*>(&wl[nb + i * 64]); \
        }                                                                     \
        const int slot = (P) * 32 + g;                                        \
        const uint4 bpa = reinterpret_cast<const uint4*>(s_bp)[slot * 2];     \
        const uint4 bpb = reinterpret_cast<const uint4*>(s_bp)[slot * 2 + 1]; \
        h2 bp[7];                                                             \
        bp[0] = __builtin_bit_cast(h2, bpa.x);                                \
        bp[1] = __builtin_bit_cast(h2, bpa.y);                                \
        bp[2] = __builtin_bit_cast(h2, bpa.z);                                \
        bp[3] = __builtin_bit_cast(h2, bpa.w);                                \
        bp[4] = __builtin_bit_cast(h2, bpb.x);                                \
        bp[5] = __builtin_bit_cast(h2, bpb.y);                                \
        bp[6] = __builtin_bit_cast(h2, bpb.z);                                \
        float a0 = 0.f, a1 = 0.f, a2 = 0.f, a3 = 0.f;                         \
        _Pragma("unroll")                                                     \
        for (int i = 0; i < 7; ++i) {                                         \
            a0 = fdot2acc(__builtin_bit_cast(h2, WCUR[i].x), bp[i], a0);      \
            a1 = fdot2acc(__builtin_bit_cast(h2, WCUR[i].y), bp[i], a1);      \
            a2 = fdot2acc(__builtin_bit_cast(h2, WCUR[i].z), bp[i], a2);      \
            a3 = fdot2acc(__builtin_bit_cast(h2, WCUR[i].w), bp[i], a3);      \
        }                                                                     \
        f4 res;                                                               \
        res.x = a0; res.y = a1; res.z = a2; res.w = a3;                       \
        reinterpret_cast<f4*>(out)[(size_t)(rbase + slot) * 8 + q] = res;     \
    }

    for (int p = 0; p < 8; p += 2) {
        ITER(p, wA, wB)
        ITER(p + 1, wB, wA)
    }
#undef ITER
}

extern "C" void kernel_launch(void* const* d_in, const int* in_sizes, int n_in,
                              void* d_out, int out_size, void* d_ws, size_t ws_size,
                              hipStream_t stream) {
    const float* times = (const float*)d_in[0];
    const int* vids = (const int*)d_in[1];
    const float* weights = (const float*)d_in[2];
    float* out = (float*)d_out;
    unsigned* wpack = (unsigned*)d_ws;

    hipLaunchKernelGGL(pack_weights_kernel, dim3(28), dim3(256), 0, stream,
                       weights, wpack);
    // 4096 blocks x 256 contiguous rays; 4 blocks/CU (37120 B LDS).
    hipLaunchKernelGGL(VideoEmbedding_kernel, dim3(4096), dim3(256), 0, stream,
                       times, vids, wpack, out);
}